// Round 2
// baseline (468.194 us; speedup 1.0000x reference)
//
#include <hip/hip_runtime.h>

#define TSEQ 512
#define BSZN 4
#define NH 16
#define NBN 32
#define EMB 1024
#define HD 64
#define TGT 1536
#define MROWS 6144

typedef unsigned short ushort_t;
typedef __bf16 bf8 __attribute__((ext_vector_type(8)));
typedef unsigned short u16x4 __attribute__((ext_vector_type(4)));
typedef float f32x4 __attribute__((ext_vector_type(4)));

__device__ __forceinline__ unsigned short f2bf(float f) {
  unsigned int u = __builtin_bit_cast(unsigned int, f);
  u += 0x7fffu + ((u >> 16) & 1u);
  return (unsigned short)(u >> 16);
}

__device__ __forceinline__ void gload16(const void* g, void* l) {
  __builtin_amdgcn_global_load_lds(
      (const __attribute__((address_space(1))) void*)g,
      (__attribute__((address_space(3))) void*)l, 16, 0, 0);
}

__device__ __forceinline__ f32x4 mfma_bf16(bf8 a, bf8 b, f32x4 c) {
  return __builtin_amdgcn_mfma_f32_16x16x32_bf16(a, b, c, 0, 0, 0);
}

// ---------------- fp32 -> bf16 convert (fused: 4 segments) ----------------
__global__ void cvt4_kernel(const float* __restrict__ q, const float* __restrict__ win,
                            const float* __restrict__ wout, const float* __restrict__ wrel,
                            ushort_t* __restrict__ qo, ushort_t* __restrict__ wino,
                            ushort_t* __restrict__ wouto, ushort_t* __restrict__ wrelo) {
  const int i = blockIdx.x * blockDim.x + threadIdx.x;
  // segment sizes in float4 units
  const int nq = 1572864, nwin = 786432, nwout = 262144, nwrel = 131072;
  const float* src;
  ushort_t* dst;
  int off;
  if (i < nq) { src = q; dst = qo; off = i; }
  else if (i < nq + nwin) { src = win; dst = wino; off = i - nq; }
  else if (i < nq + nwin + nwout) { src = wout; dst = wouto; off = i - nq - nwin; }
  else if (i < nq + nwin + nwout + nwrel) { src = wrel; dst = wrelo; off = i - nq - nwin - nwout; }
  else return;
  const float4 v = reinterpret_cast<const float4*>(src)[off];
  ushort4 o;
  o.x = f2bf(v.x); o.y = f2bf(v.y); o.z = f2bf(v.z); o.w = f2bf(v.w);
  reinterpret_cast<ushort4*>(dst)[off] = o;
}

// ---------------- GEMM: C[M,N] = A[M,K] * B[N,K]^T + bias ----------------
template <int MODE>
__global__ __launch_bounds__(256) void gemm_bt(
    const ushort_t* __restrict__ A, const ushort_t* __restrict__ B,
    const float* __restrict__ bias, float* __restrict__ Cf,
    ushort_t* __restrict__ Qo, ushort_t* __restrict__ Ko, ushort_t* __restrict__ Vto,
    int M, int N, int K) {
  __shared__ ushort_t lA[128 * 32];
  __shared__ ushort_t lB[128 * 32];
  const int tid = threadIdx.x;
  const int lane = tid & 63;
  const int wid = tid >> 6;
  const int l15 = lane & 15, l4 = lane >> 4;
  const int bm = blockIdx.y, bn = blockIdx.x;
  const int wm = (wid >> 1) * 64, wn = (wid & 1) * 64;

  f32x4 acc[4][4] = {};

  const int srow = tid >> 2;
  const int scol = (tid & 3) * 8;
  const ushort_t* Ag = A + (size_t)(bm * 128 + srow) * K + scol;
  const ushort_t* Bg = B + (size_t)(bn * 128 + srow) * K + scol;
  ushort_t* lAp = &lA[srow * 32 + scol];
  ushort_t* lBp = &lB[srow * 32 + scol];

  for (int kt = 0; kt < K; kt += 32) {
    __syncthreads();
    gload16(Ag + kt, lAp);
    gload16(Ag + kt + (size_t)64 * K, lAp + 64 * 32);
    gload16(Bg + kt, lBp);
    gload16(Bg + kt + (size_t)64 * K, lBp + 64 * 32);
    __syncthreads();
    bf8 af[4], bv[4];
#pragma unroll
    for (int mi = 0; mi < 4; ++mi)
      af[mi] = *reinterpret_cast<const bf8*>(&lA[(wm + mi * 16 + l15) * 32 + l4 * 8]);
#pragma unroll
    for (int ni = 0; ni < 4; ++ni)
      bv[ni] = *reinterpret_cast<const bf8*>(&lB[(wn + ni * 16 + l15) * 32 + l4 * 8]);
#pragma unroll
    for (int mi = 0; mi < 4; ++mi)
#pragma unroll
      for (int ni = 0; ni < 4; ++ni)
        acc[mi][ni] = mfma_bf16(af[mi], bv[ni], acc[mi][ni]);
  }

#pragma unroll
  for (int ni = 0; ni < 4; ++ni) {
    const int col = bn * 128 + wn + ni * 16 + l15;
    const float bc = bias[col];
#pragma unroll
    for (int mi = 0; mi < 4; ++mi) {
      const int row0 = bm * 128 + wm + mi * 16 + l4 * 4;
      f32x4 v = acc[mi][ni];
#pragma unroll
      for (int r = 0; r < 4; ++r) {
        const int row = row0 + r;
        float val = v[r] + bc;
        if (MODE == 0) {
          const int part = col >> 10;
          const int cc = col & 1023;
          const int h = cc >> 6, d = cc & 63;
          const int t = row >> 2, bb = row & 3;
          const int bh = bb * NH + h;
          if (part == 0) {
            Qo[((size_t)bh * TGT + t) * HD + d] = f2bf(val * 0.125f);
          } else if (part == 1) {
            Ko[((size_t)bh * TGT + t) * HD + d] = f2bf(val);
          } else {
            Vto[((size_t)bh * HD + d) * TGT + t] = f2bf(val);
          }
        } else {
          Cf[(size_t)row * N + col] = val;
        }
      }
    }
  }
}

// ---------------- fused attention (main + ngram), flash-style ----------------
// grid: (h 0..15, tile*4+b 0..127, z 0..2)  z=0 main, z=1,2 ngram g=z-1
// h fastest so the 16 blocks sharing (b,tile)'s ib/mask/VM rows are coscheduled.
__global__ __launch_bounds__(256, 4) void attn_kernel(
    const ushort_t* __restrict__ Q, const ushort_t* __restrict__ Kb,
    const ushort_t* __restrict__ Vt, const float* __restrict__ VM,
    const int* __restrict__ ib_main, const int* __restrict__ ib_rel,
    const float* __restrict__ mask_main, const float* __restrict__ mask_ng,
    ushort_t* __restrict__ AT) {
  __shared__ float S[16][516];          // P (bf16) overwrites each row in place
  __shared__ float red_m[16], red_s[16], red_r[16];
  ushort_t* Pb = reinterpret_cast<ushort_t*>(&S[0][0]);  // row stride 1032 ushorts

  const int h = blockIdx.x;
  const int tile = blockIdx.y >> 2;
  const int b = blockIdx.y & 3;
  const int z = blockIdx.z;
  const int bh = b * NH + h;
  const int t0 = tile * 16;
  const int tid = threadIdx.x;
  const int lane = tid & 63, wid = tid >> 6;
  const int l15 = lane & 15, l4 = lane >> 4;

  const int g = z - 1;
  const int nchunk = (z == 0) ? 1 : 2;
  const int qrow0 = (z == 0) ? t0 : TSEQ + g * TSEQ + t0;

  if (tid < 16) { red_m[tid] = -1e30f; red_s[tid] = 0.f; }

  const ushort_t* qp = &Q[((size_t)bh * TGT + qrow0 + l15) * HD + l4 * 8];
  bf8 qf0 = *reinterpret_cast<const bf8*>(qp);
  bf8 qf1 = *reinterpret_cast<const bf8*>(qp + 32);

  f32x4 oacc = {};
  const int d0 = wid * 16;

  for (int ch = 0; ch < nchunk; ++ch) {
    const int srow0 = (ch == 0) ? 0 : TSEQ + g * TSEQ;

    // ---- prefetch bucket indices for this wave's 4 rows (hidden under QK MFMA)
    int4 iba[4], ibb[4];
#pragma unroll
    for (int rr = 0; rr < 4; ++rr) {
      const int tloc = t0 + wid * 4 + rr;
      const int* ibrow = (z == 0)
          ? ib_main + ((size_t)b * TSEQ + tloc) * TSEQ
          : ib_rel + ((size_t)b * TSEQ + tloc) * (2 * TSEQ) + ch * TSEQ;
      iba[rr] = *reinterpret_cast<const int4*>(ibrow + lane * 4);
      ibb[rr] = *reinterpret_cast<const int4*>(ibrow + 256 + lane * 4);
    }

    // ---- QK^T: this wave covers cols [wid*128, wid*128+128)
#pragma unroll
    for (int ni = 0; ni < 8; ++ni) {
      const int s0 = wid * 128 + ni * 16;
      const ushort_t* kp = &Kb[((size_t)bh * TGT + srow0 + s0 + l15) * HD + l4 * 8];
      bf8 kf0 = *reinterpret_cast<const bf8*>(kp);
      bf8 kf1 = *reinterpret_cast<const bf8*>(kp + 32);
      f32x4 s4 = {};
      __builtin_amdgcn_s_setprio(1);
      s4 = mfma_bf16(qf0, kf0, s4);
      s4 = mfma_bf16(qf1, kf1, s4);
      __builtin_amdgcn_s_setprio(0);
#pragma unroll
      for (int r = 0; r < 4; ++r) S[l4 * 4 + r][s0 + l15] = s4[r];
    }
    __syncthreads();

    // ---- softmax + rel gather + mask: wave owns rows wid*4..wid*4+3
    // lane owns cols {lane*4..+3} and {256+lane*4..+3} (conflict-free float4)
    u16x4 plo[4], phi[4];
#pragma unroll
    for (int rr = 0; rr < 4; ++rr) {
      const int r = wid * 4 + rr;
      const int tloc = t0 + r;
      const int qglob = qrow0 + r;
      const float* mrow = (z == 0)
          ? mask_main + (size_t)tloc * TSEQ
          : mask_ng + ((size_t)g * TSEQ + tloc) * (2 * TSEQ) + ch * TSEQ;
      const float* vmp = VM + (size_t)(qglob * BSZN + b) * (NBN * NH);
      const float4 mk0 = *reinterpret_cast<const float4*>(mrow + lane * 4);
      const float4 mk1 = *reinterpret_cast<const float4*>(mrow + 256 + lane * 4);
      const float4 s0 = *reinterpret_cast<const float4*>(&S[r][lane * 4]);
      const float4 s1 = *reinterpret_cast<const float4*>(&S[r][256 + lane * 4]);
      float vals[8];
      vals[0] = s0.x + vmp[iba[rr].x * NH + h] + mk0.x;
      vals[1] = s0.y + vmp[iba[rr].y * NH + h] + mk0.y;
      vals[2] = s0.z + vmp[iba[rr].z * NH + h] + mk0.z;
      vals[3] = s0.w + vmp[iba[rr].w * NH + h] + mk0.w;
      vals[4] = s1.x + vmp[ibb[rr].x * NH + h] + mk1.x;
      vals[5] = s1.y + vmp[ibb[rr].y * NH + h] + mk1.y;
      vals[6] = s1.z + vmp[ibb[rr].z * NH + h] + mk1.z;
      vals[7] = s1.w + vmp[ibb[rr].w * NH + h] + mk1.w;
      float mx = fmaxf(fmaxf(fmaxf(vals[0], vals[1]), fmaxf(vals[2], vals[3])),
                       fmaxf(fmaxf(vals[4], vals[5]), fmaxf(vals[6], vals[7])));
#pragma unroll
      for (int off = 32; off > 0; off >>= 1) mx = fmaxf(mx, __shfl_xor(mx, off));
      const float oldm = red_m[r];
      const float newm = fmaxf(oldm, mx);
      float sum = 0.f;
#pragma unroll
      for (int j = 0; j < 4; ++j) {
        const float p = __expf(vals[j] - newm);
        sum += p;
        plo[rr][j] = f2bf(p);
      }
#pragma unroll
      for (int j = 0; j < 4; ++j) {
        const float p = __expf(vals[4 + j] - newm);
        sum += p;
        phi[rr][j] = f2bf(p);
      }
#pragma unroll
      for (int off = 32; off > 0; off >>= 1) sum += __shfl_xor(sum, off);
      if (lane == 0) {
        const float rsc = (oldm <= -1e30f) ? 0.f : __expf(oldm - newm);
        red_r[r] = rsc;
        red_s[r] = red_s[r] * rsc + sum;
        red_m[r] = newm;
      }
    }
    // all S reads for this wave's rows are done; now overwrite rows with bf16 P
    asm volatile("" ::: "memory");
    __builtin_amdgcn_sched_barrier(0);
#pragma unroll
    for (int rr = 0; rr < 4; ++rr) {
      const int r = wid * 4 + rr;
      *reinterpret_cast<u16x4*>(Pb + (size_t)r * 1032 + lane * 4) = plo[rr];
      *reinterpret_cast<u16x4*>(Pb + (size_t)r * 1032 + 256 + lane * 4) = phi[rr];
    }
    __syncthreads();

    // ---- rescale + PV: this wave owns d-tile d0 = wid*16
    {
      f32x4 rs;
#pragma unroll
      for (int r = 0; r < 4; ++r) rs[r] = red_r[l4 * 4 + r];
      oacc *= rs;
    }
#pragma unroll
    for (int ks = 0; ks < 16; ++ks) {
      bf8 pa = *reinterpret_cast<const bf8*>(&Pb[(size_t)l15 * 1032 + ks * 32 + l4 * 8]);
      bf8 vb = *reinterpret_cast<const bf8*>(
          &Vt[((size_t)bh * HD + d0 + l15) * TGT + srow0 + ks * 32 + l4 * 8]);
      __builtin_amdgcn_s_setprio(1);
      oacc = mfma_bf16(pa, vb, oacc);
      __builtin_amdgcn_s_setprio(0);
    }
    __syncthreads();
  }

#pragma unroll
  for (int r = 0; r < 4; ++r) {
    const int row = l4 * 4 + r;
    const float inv = 1.f / red_s[row];
    const int tout = qrow0 + row;
    AT[((size_t)tout * BSZN + b) * EMB + h * HD + d0 + l15] = f2bf(oacc[r] * inv);
  }
}

extern "C" void kernel_launch(void* const* d_in, const int* in_sizes, int n_in,
                              void* d_out, int out_size, void* d_ws, size_t ws_size,
                              hipStream_t stream) {
  const float* query     = (const float*)d_in[0];
  const float* mask_main = (const float*)d_in[1];
  const float* mask_ng   = (const float*)d_in[2];
  const int*   ib_main   = (const int*)d_in[3];
  const int*   ib_rel    = (const int*)d_in[4];
  const float* w_in      = (const float*)d_in[5];
  const float* b_in      = (const float*)d_in[6];
  const float* w_out     = (const float*)d_in[7];
  const float* b_out     = (const float*)d_in[8];
  const float* w_rel     = (const float*)d_in[9];
  const float* b_rel     = (const float*)d_in[10];
  float* out = (float*)d_out;

  ushort_t* qbf    = (ushort_t*)d_ws;           // 6144*1024
  ushort_t* winbf  = qbf + 6291456;             // 3072*1024
  ushort_t* woutbf = winbf + 3145728;           // 1024*1024
  ushort_t* relwbf = woutbf + 1048576;          // 512*1024
  ushort_t* Qb     = relwbf + 524288;           // 64*1536*64
  ushort_t* Kbuf   = Qb + 6291456;
  ushort_t* Vtb    = Kbuf + 6291456;
  float*    VM     = (float*)(Vtb + 6291456);   // 6144*512 fp32
  ushort_t* AT     = (ushort_t*)(VM + 3145728); // 6144*1024

  // fp32 -> bf16 (single fused launch)
  {
    const int total4 = 1572864 + 786432 + 262144 + 131072;
    cvt4_kernel<<<(total4 + 255) / 256, 256, 0, stream>>>(query, w_in, w_out, w_rel,
                                                          qbf, winbf, woutbf, relwbf);
  }

  // in-projection -> Q/K/Vt
  gemm_bt<0><<<dim3(24, 48), 256, 0, stream>>>(qbf, winbf, b_in, nullptr,
                                               Qb, Kbuf, Vtb, MROWS, 3072, 1024);
  // relative-value table VM
  gemm_bt<1><<<dim3(4, 48), 256, 0, stream>>>(qbf, relwbf, b_rel, VM,
                                              nullptr, nullptr, nullptr, MROWS, 512, 1024);
  // fused attention (main + 2 ngram streams)
  attn_kernel<<<dim3(16, 128, 3), 256, 0, stream>>>(Qb, Kbuf, Vtb, VM, ib_main, ib_rel,
                                                    mask_main, mask_ng, AT);
  // out-projection
  gemm_bt<2><<<dim3(8, 48), 256, 0, stream>>>(AT, woutbf, b_out, out,
                                              nullptr, nullptr, nullptr, MROWS, 1024, 1024);
}